// Round 4
// baseline (1456.994 us; speedup 1.0000x reference)
//
#include <hip/hip_runtime.h>

// LSTMFeatureExtractor: 2-layer LSTM (H=128) over B=512, T=512, + a*relu(a) head.
// Round 4: input projection x@Wih^T moved OFF the recurrent critical path.
// Per 4-step chunk: batched projection (Wih f16 frags streamed from ws, outputs
// accumulated in 16 register C-frags "gpre"), then 4 light recurrence steps
// (only h@Whh^T, 16 MFMAs, seeded with gpre). Whh stays in VGPRs; Wih was
// evicted from the register file (round-2/3 were at the 256-reg occupancy edge).
// Roles pipelined as before (role0 layer0 -> ws, role1 layer1+head), 4-step flags.

typedef _Float16 half8  __attribute__((ext_vector_type(8)));
typedef _Float16 half4_ __attribute__((ext_vector_type(4)));
typedef float    f32x4  __attribute__((ext_vector_type(4)));

#define H_    128
#define T_    512
#define B_    512
#define BCH   16              // batch per block
#define NBG   (B_ / BCH)      // 32 batch groups
#define TCH   4               // timesteps per chunk (pipeline granularity)
#define NCH   (T_ / TCH)      // 128 chunks
#define KPAD  136             // padded LDS row

#define LOG2E 1.44269504089f

__device__ __forceinline__ float sigm_(float x) {
    return __builtin_amdgcn_rcpf(1.f + __builtin_amdgcn_exp2f(-LOG2E * x));
}
__device__ __forceinline__ float tanh_(float x) {
    return 1.f - 2.f * __builtin_amdgcn_rcpf(1.f + __builtin_amdgcn_exp2f((2.f * LOG2E) * x));
}

#define MFMA16(A, Bv, C) __builtin_amdgcn_mfma_f32_16x16x32_f16((A), (Bv), (C), 0, 0, 0)

// Convert Wih0/Wih1 (f32 [512][128]) to f16 in frag-consumption order:
// index = ((((layer*8+w)*4+gt)*4+kt)*64 + l) * 8 halves.
// lane l holds A[row = gt*128+w*16+(l&15)][col = kt*32+(l>>4)*8 + e], e=0..7.
__global__ void __launch_bounds__(256)
prep_wih(const float* __restrict__ Wih0, const float* __restrict__ Wih1,
         _Float16* __restrict__ wihF) {
    const int t = blockIdx.x * 256 + threadIdx.x;   // 0..16383
    const int l     = t & 63;
    const int kt    = (t >> 6) & 3;
    const int gt    = (t >> 8) & 3;
    const int w     = (t >> 10) & 7;
    const int layer = (t >> 13) & 1;
    const float* W = layer ? Wih1 : Wih0;
    const int row = gt * 128 + w * 16 + (l & 15);
    const int col = kt * 32 + (l >> 4) * 8;
    const float* p = W + row * H_ + col;
    f32x4 a0 = *(const f32x4*)(p);
    f32x4 a1 = *(const f32x4*)(p + 4);
    half8 h;
    #pragma unroll
    for (int e = 0; e < 4; ++e) { h[e] = (_Float16)a0[e]; h[e + 4] = (_Float16)a1[e]; }
    *(half8*)(wihF + (size_t)t * 8) = h;
}

// role 0: layer0. x staged from y (fp32 [b][k][t]) -> xbuf; h stored per step to
//         h0ws (f16 [b][t][u]); flag released per chunk.
// role 1: layer1. x frags read DIRECT from h0ws (global, L2-hot) after flag
//         acquire; fused Wa head + sum a*relu(a) -> out.
__global__ void __launch_bounds__(512)
lstm_fused(const float* __restrict__ y,
           const float* __restrict__ Wih0, const float* __restrict__ Whh0,
           const float* __restrict__ bih0, const float* __restrict__ bhh0,
           const float* __restrict__ Wih1, const float* __restrict__ Whh1,
           const float* __restrict__ bih1, const float* __restrict__ bhh1,
           const float* __restrict__ Wa,  const float* __restrict__ ba,
           const _Float16* __restrict__ wihF,   // f16 frag-ordered Wih (or nullptr)
           _Float16* __restrict__ h0ws,
           int* __restrict__ flags,
           float* __restrict__ out,
           int roleBase, int doPipe)
{
    __shared__ _Float16 xbuf[TCH][16][KPAD];   // role-0 x chunk
    __shared__ _Float16 hbuf[2][16][KPAD];     // double-buffered h

    const int tid  = threadIdx.x;
    const int w    = tid >> 6;
    const int l    = tid & 63;
    const int g    = l >> 4;
    const int cl   = l & 15;
    const int role = (blockIdx.x >> 5) + roleBase;   // block-uniform
    const int bg   = blockIdx.x & 31;
    const int b0   = bg * BCH;

    // ---- zero LDS (initial h state; hygiene) ----
    {
        int* p = (int*)&xbuf[0][0][0];
        for (int i = tid; i < (int)(sizeof(xbuf) / 4); i += 512) p[i] = 0;
        int* q = (int*)&hbuf[0][0][0];
        for (int i = tid; i < (int)(sizeof(hbuf) / 4); i += 512) q[i] = 0;
    }

    const float* Wih  = role ? Wih1 : Wih0;
    const float* Whh  = role ? Whh1 : Whh0;
    const float* bihp = role ? bih1 : bih0;
    const float* bhhp = role ? bhh1 : bhh0;

    // ---- Whh A-fragments in registers (64 VGPR) ----
    half8 whhf[4][4];
    #pragma unroll
    for (int gt = 0; gt < 4; ++gt) {
        const int grow = gt * 128 + w * 16 + cl;
        #pragma unroll
        for (int kt = 0; kt < 4; ++kt) {
            const float* pb = Whh + grow * H_ + kt * 32 + g * 8;
            f32x4 c0 = *(const f32x4*)(pb);
            f32x4 c1 = *(const f32x4*)(pb + 4);
            half8 fb;
            #pragma unroll
            for (int e = 0; e < 4; ++e) { fb[e] = (_Float16)c0[e]; fb[e + 4] = (_Float16)c1[e]; }
            whhf[gt][kt] = fb;
        }
    }

    // combined bias in C-frag layout
    f32x4 bias[4];
    #pragma unroll
    for (int gt = 0; gt < 4; ++gt)
        #pragma unroll
        for (int r = 0; r < 4; ++r) {
            const int R = gt * 128 + w * 16 + g * 4 + r;
            bias[gt][r] = bihp[R] + bhhp[R];
        }

    half8 waf[4];
    f32x4 ba4  = {0.f, 0.f, 0.f, 0.f};
    f32x4 oacc = {0.f, 0.f, 0.f, 0.f};
    if (role == 1) {
        #pragma unroll
        for (int kt = 0; kt < 4; ++kt) {
            const float* p = Wa + (w * 16 + cl) * H_ + kt * 32 + g * 8;
            f32x4 a0 = *(const f32x4*)(p);
            f32x4 a1 = *(const f32x4*)(p + 4);
            half8 f;
            #pragma unroll
            for (int e = 0; e < 4; ++e) { f[e] = (_Float16)a0[e]; f[e + 4] = (_Float16)a1[e]; }
            waf[kt] = f;
        }
        #pragma unroll
        for (int r = 0; r < 4; ++r) ba4[r] = ba[w * 16 + g * 4 + r];
    }

    float cst[4] = {0.f, 0.f, 0.f, 0.f};
    __syncthreads();

    for (int c = 0; c < NCH; ++c) {
        const int t0 = c * TCH;

        // ============ chunk prologue: stage / acquire ============
        if (role == 0) {
            // stage y[b][k][t0..t0+3] -> xbuf (f16); one f32x4 per (b,k)
            #pragma unroll
            for (int rr = 0; rr < 4; ++rr) {
                const int q = tid + rr * 512;       // 0..2047
                const int b = q >> 7, k = q & 127;
                const float* src = y + ((size_t)((b0 + b) * H_ + k)) * T_ + t0;
                f32x4 v = *(const f32x4*)(src);
                #pragma unroll
                for (int e = 0; e < 4; ++e) xbuf[e][b][k] = (_Float16)v[e];
            }
            __syncthreads();
        } else if (doPipe) {
            if (tid == 0) {
                while (__hip_atomic_load(&flags[bg], __ATOMIC_ACQUIRE,
                                         __HIP_MEMORY_SCOPE_AGENT) < c + 1)
                    __builtin_amdgcn_s_sleep(2);
            }
            __syncthreads();
        }

        // ============ projection phase: gpre = bias + Wih * x ============
        f32x4 gpre[TCH][4];
        #pragma unroll
        for (int tb = 0; tb < TCH; ++tb)
            #pragma unroll
            for (int gt = 0; gt < 4; ++gt) gpre[tb][gt] = bias[gt];

        #pragma unroll
        for (int kt = 0; kt < 4; ++kt) {
            half8 wf[4];
            if (wihF) {
                #pragma unroll
                for (int gt = 0; gt < 4; ++gt) {
                    const size_t fi = ((((size_t)role * 8 + w) * 4 + gt) * 4 + kt) * 64 + l;
                    wf[gt] = *(const half8*)(wihF + fi * 8);
                }
            } else {
                #pragma unroll
                for (int gt = 0; gt < 4; ++gt) {
                    const float* pa = Wih + (gt * 128 + w * 16 + cl) * H_ + kt * 32 + g * 8;
                    f32x4 a0 = *(const f32x4*)(pa);
                    f32x4 a1 = *(const f32x4*)(pa + 4);
                    half8 f;
                    #pragma unroll
                    for (int e = 0; e < 4; ++e) { f[e] = (_Float16)a0[e]; f[e + 4] = (_Float16)a1[e]; }
                    wf[gt] = f;
                }
            }
            #pragma unroll
            for (int tb = 0; tb < TCH; ++tb) {
                half8 xf;
                if (role == 0) {
                    xf = *(const half8*)&xbuf[tb][cl][kt * 32 + g * 8];
                } else {
                    const _Float16* hsrc =
                        h0ws + ((size_t)(b0 + cl) * T_ + (t0 + tb)) * H_ + kt * 32 + g * 8;
                    xf = *(const half8*)hsrc;
                }
                gpre[tb][0] = MFMA16(wf[0], xf, gpre[tb][0]);
                gpre[tb][1] = MFMA16(wf[1], xf, gpre[tb][1]);
                gpre[tb][2] = MFMA16(wf[2], xf, gpre[tb][2]);
                gpre[tb][3] = MFMA16(wf[3], xf, gpre[tb][3]);
            }
        }

        // ============ recurrence: 4 light steps ============
        #pragma unroll
        for (int tb = 0; tb < TCH; ++tb) {
            const int rd = (tb + 1) & 1;   // h(t-1) parity (TCH even)
            const int wr = tb & 1;
            const int t  = t0 + tb;

            half8 hf[4];
            #pragma unroll
            for (int kt = 0; kt < 4; ++kt)
                hf[kt] = *(const half8*)&hbuf[rd][cl][kt * 32 + g * 8];

            f32x4 a0 = gpre[tb][0], a1 = gpre[tb][1], a2 = gpre[tb][2], a3 = gpre[tb][3];
            #pragma unroll
            for (int kt = 0; kt < 4; ++kt) {
                a0 = MFMA16(whhf[0][kt], hf[kt], a0);
                a1 = MFMA16(whhf[1][kt], hf[kt], a1);
                a2 = MFMA16(whhf[2][kt], hf[kt], a2);
                a3 = MFMA16(whhf[3][kt], hf[kt], a3);
            }

            if (role == 1) {
                if (c > 0 || tb > 0) {   // head term for h1(t-1)
                    f32x4 aacc = ba4;
                    #pragma unroll
                    for (int kt = 0; kt < 4; ++kt) aacc = MFMA16(waf[kt], hf[kt], aacc);
                    #pragma unroll
                    for (int r = 0; r < 4; ++r) {
                        const float a = aacc[r];
                        oacc[r] += a * fmaxf(a, 0.f);
                    }
                }
            }

            half4_ h4;
            #pragma unroll
            for (int r = 0; r < 4; ++r) {
                const float is  = sigm_(a0[r]);
                const float fs  = sigm_(a1[r]);
                const float gt_ = tanh_(a2[r]);
                const float os  = sigm_(a3[r]);
                cst[r] = fs * cst[r] + is * gt_;
                h4[r] = (_Float16)(os * tanh_(cst[r]));
            }
            const int u0 = w * 16 + g * 4;
            *(half4_*)&hbuf[wr][cl][u0] = h4;
            if (role == 0) {
                *(half4_*)&h0ws[((size_t)(b0 + cl) * T_ + t) * H_ + u0] = h4;
            }
            __syncthreads();
        }

        if (role == 0 && doPipe) {
            if (tid == 0)
                __hip_atomic_store(&flags[bg], c + 1, __ATOMIC_RELEASE,
                                   __HIP_MEMORY_SCOPE_AGENT);
        }
    }

    if (role == 1) {
        // final head term for h1(T-1): last write parity tb=3 -> hbuf[1]
        f32x4 aacc = ba4;
        #pragma unroll
        for (int kt = 0; kt < 4; ++kt) {
            const half8 hfv = *(const half8*)&hbuf[1][cl][kt * 32 + g * 8];
            aacc = MFMA16(waf[kt], hfv, aacc);
        }
        #pragma unroll
        for (int r = 0; r < 4; ++r) {
            const float a = aacc[r];
            oacc[r] += a * fmaxf(a, 0.f);
        }
        *(f32x4*)&out[(size_t)(b0 + cl) * H_ + w * 16 + g * 4] = oacc;
    }
}

extern "C" void kernel_launch(void* const* d_in, const int* in_sizes, int n_in,
                              void* d_out, int out_size, void* d_ws, size_t ws_size,
                              hipStream_t stream) {
    const float* y    = (const float*)d_in[0];
    const float* Wih0 = (const float*)d_in[1];
    const float* Whh0 = (const float*)d_in[2];
    const float* bih0 = (const float*)d_in[3];
    const float* bhh0 = (const float*)d_in[4];
    const float* Wih1 = (const float*)d_in[5];
    const float* Whh1 = (const float*)d_in[6];
    const float* bih1 = (const float*)d_in[7];
    const float* bhh1 = (const float*)d_in[8];
    const float* Wa   = (const float*)d_in[9];
    const float* ba   = (const float*)d_in[10];
    float* out = (float*)d_out;

    const size_t H0_BYTES = (size_t)B_ * T_ * H_ * sizeof(_Float16); // 64 MiB
    const size_t FLAG_OFF = H0_BYTES;                                // 512 B
    const size_t WF_OFF   = H0_BYTES + 512;
    const size_t WF_BYTES = (size_t)16384 * 16;                      // 256 KiB

    _Float16* h0ws = (_Float16*)d_ws;
    _Float16* wihF = nullptr;
    if (ws_size >= WF_OFF + WF_BYTES) {
        wihF = (_Float16*)((char*)d_ws + WF_OFF);
        prep_wih<<<64, 256, 0, stream>>>(Wih0, Wih1, wihF);
    }

    if (ws_size >= H0_BYTES + 512) {
        int* flags = (int*)((char*)d_ws + FLAG_OFF);
        hipMemsetAsync(flags, 0, 512, stream);
        lstm_fused<<<2 * NBG, 512, 0, stream>>>(y, Wih0, Whh0, bih0, bhh0,
                                                Wih1, Whh1, bih1, bhh1, Wa, ba,
                                                wihF, h0ws, flags, out, 0, 1);
    } else {
        lstm_fused<<<NBG, 512, 0, stream>>>(y, Wih0, Whh0, bih0, bhh0,
                                            Wih1, Whh1, bih1, bhh1, Wa, ba,
                                            wihF, h0ws, nullptr, out, 0, 0);
        lstm_fused<<<NBG, 512, 0, stream>>>(y, Wih0, Whh0, bih0, bhh0,
                                            Wih1, Whh1, bih1, bhh1, Wa, ba,
                                            wihF, h0ws, nullptr, out, 1, 0);
    }
}

// Round 5
// 1197.247 us; speedup vs baseline: 1.2170x; 1.2170x over previous
//
#include <hip/hip_runtime.h>

// LSTMFeatureExtractor: 2-layer LSTM (H=128) over B=512, T=512, + a*relu(a) head.
// Round 5 = round-2 structure (best: 860us) + latency hiding:
//  (1) role-0's per-step global h store is DELAYED: issued right after the step
//      barrier (retires during the next step), so the next barrier's implicit
//      vmcnt(0) drain doesn't stall ~400-900cyc. tb==7 stores immediately so the
//      chunk flag release still covers all stores.
//  (2) next chunk's y is prefetched into registers after tb==2's barrier;
//      chunk-start staging is then LDS-writes only (no global latency on path).
//  (3) per-step fragment reads hoisted to step top, xf before hf.

typedef _Float16 half8  __attribute__((ext_vector_type(8)));
typedef _Float16 half4_ __attribute__((ext_vector_type(4)));
typedef float    f32x4  __attribute__((ext_vector_type(4)));

#define H_    128
#define T_    512
#define B_    512
#define BCH   16              // batch per block
#define NBG   (B_ / BCH)      // 32 batch groups
#define TCH   8               // timesteps per chunk (pipeline granularity)
#define NCH   (T_ / TCH)      // 64 chunks
#define KPAD  136             // padded LDS row: 272B

#define LOG2E 1.44269504089f

__device__ __forceinline__ float sigm_(float x) {
    return __builtin_amdgcn_rcpf(1.f + __builtin_amdgcn_exp2f(-LOG2E * x));
}
__device__ __forceinline__ float tanh_(float x) {
    return 1.f - 2.f * __builtin_amdgcn_rcpf(1.f + __builtin_amdgcn_exp2f((2.f * LOG2E) * x));
}

#define MFMA16(A, Bv, C) __builtin_amdgcn_mfma_f32_16x16x32_f16((A), (Bv), (C), 0, 0, 0)

__global__ void __launch_bounds__(512)
lstm_fused(const float* __restrict__ y,
           const float* __restrict__ Wih0, const float* __restrict__ Whh0,
           const float* __restrict__ bih0, const float* __restrict__ bhh0,
           const float* __restrict__ Wih1, const float* __restrict__ Whh1,
           const float* __restrict__ bih1, const float* __restrict__ bhh1,
           const float* __restrict__ Wa,  const float* __restrict__ ba,
           _Float16* __restrict__ h0ws,
           int* __restrict__ flags,
           float* __restrict__ out,
           int roleBase, int doPipe)
{
    __shared__ _Float16 xbuf[TCH][16][KPAD];
    __shared__ _Float16 hbuf[2][16][KPAD];

    const int tid  = threadIdx.x;
    const int w    = tid >> 6;
    const int l    = tid & 63;
    const int g    = l >> 4;
    const int cl   = l & 15;
    const int role = (blockIdx.x >> 5) + roleBase;   // block-uniform
    const int bg   = blockIdx.x & 31;
    const int b0   = bg * BCH;

    // ---- zero LDS ----
    {
        int* p = (int*)&xbuf[0][0][0];
        for (int i = tid; i < (int)(sizeof(xbuf) / 4); i += 512) p[i] = 0;
        int* q = (int*)&hbuf[0][0][0];
        for (int i = tid; i < (int)(sizeof(hbuf) / 4); i += 512) q[i] = 0;
    }

    const float* Wih  = role ? Wih1 : Wih0;
    const float* Whh  = role ? Whh1 : Whh0;
    const float* bihp = role ? bih1 : bih0;
    const float* bhhp = role ? bhh1 : bhh0;

    // ---- weight A-fragments in registers ----
    half8 wihf[4][4], whhf[4][4];
    #pragma unroll
    for (int gt = 0; gt < 4; ++gt) {
        const int grow = gt * 128 + w * 16 + cl;
        #pragma unroll
        for (int kt = 0; kt < 4; ++kt) {
            const float* pa = Wih + grow * H_ + kt * 32 + g * 8;
            const float* pb = Whh + grow * H_ + kt * 32 + g * 8;
            f32x4 a0 = *(const f32x4*)(pa);
            f32x4 a1 = *(const f32x4*)(pa + 4);
            f32x4 c0 = *(const f32x4*)(pb);
            f32x4 c1 = *(const f32x4*)(pb + 4);
            half8 fa, fb;
            #pragma unroll
            for (int e = 0; e < 4; ++e) {
                fa[e] = (_Float16)a0[e]; fa[e + 4] = (_Float16)a1[e];
                fb[e] = (_Float16)c0[e]; fb[e + 4] = (_Float16)c1[e];
            }
            wihf[gt][kt] = fa; whhf[gt][kt] = fb;
        }
    }

    f32x4 bias[4];
    #pragma unroll
    for (int gt = 0; gt < 4; ++gt)
        #pragma unroll
        for (int r = 0; r < 4; ++r) {
            const int R = gt * 128 + w * 16 + g * 4 + r;
            bias[gt][r] = bihp[R] + bhhp[R];
        }

    half8 waf[4];
    f32x4 ba4  = {0.f, 0.f, 0.f, 0.f};
    f32x4 oacc = {0.f, 0.f, 0.f, 0.f};
    if (role == 1) {
        #pragma unroll
        for (int kt = 0; kt < 4; ++kt) {
            const float* p = Wa + (w * 16 + cl) * H_ + kt * 32 + g * 8;
            f32x4 a0 = *(const f32x4*)(p);
            f32x4 a1 = *(const f32x4*)(p + 4);
            half8 f;
            #pragma unroll
            for (int e = 0; e < 4; ++e) { f[e] = (_Float16)a0[e]; f[e + 4] = (_Float16)a1[e]; }
            waf[kt] = f;
        }
        #pragma unroll
        for (int r = 0; r < 4; ++r) ba4[r] = ba[w * 16 + g * 4 + r];
    }

    float cst[4] = {0.f, 0.f, 0.f, 0.f};
    half4_ h4p;                     // role-0 delayed-store payload
    f32x4 pf0[4], pf1[4];           // role-0 y prefetch (next chunk), 32 VGPR

    __syncthreads();

    for (int t = 0; t < T_; ++t) {
        const int tb = t & (TCH - 1);
        const int c  = t >> 3;

        // ---- delayed h store: issued just after previous barrier ----
        if (role == 0 && tb >= 1) {
            const int u0 = w * 16 + g * 4;
            *(half4_*)&h0ws[((size_t)(b0 + cl) * T_ + (t - 1)) * H_ + u0] = h4p;
        }

        // ---- y prefetch for next chunk (retires during this step) ----
        if (role == 0 && tb == 2 && c + 1 < NCH) {
            const int tn = (c + 1) * TCH;
            #pragma unroll
            for (int rr = 0; rr < 4; ++rr) {
                const int q = tid + rr * 512;
                const int b = q >> 7, k = q & 127;
                const float* src = y + ((size_t)((b0 + b) * H_ + k)) * T_ + tn;
                pf0[rr] = *(const f32x4*)(src);
                pf1[rr] = *(const f32x4*)(src + 4);
            }
        }

        // ---- chunk prologue ----
        if (tb == 0) {
            if (role == 0) {
                if (c == 0) {
                    #pragma unroll
                    for (int rr = 0; rr < 4; ++rr) {
                        const int q = tid + rr * 512;
                        const int b = q >> 7, k = q & 127;
                        const float* src = y + ((size_t)((b0 + b) * H_ + k)) * T_ + t;
                        f32x4 v0 = *(const f32x4*)(src);
                        f32x4 v1 = *(const f32x4*)(src + 4);
                        #pragma unroll
                        for (int e = 0; e < 4; ++e) {
                            xbuf[e][b][k]     = (_Float16)v0[e];
                            xbuf[e + 4][b][k] = (_Float16)v1[e];
                        }
                    }
                } else {
                    // stage from prefetch registers — no global latency here
                    #pragma unroll
                    for (int rr = 0; rr < 4; ++rr) {
                        const int q = tid + rr * 512;
                        const int b = q >> 7, k = q & 127;
                        #pragma unroll
                        for (int e = 0; e < 4; ++e) {
                            xbuf[e][b][k]     = (_Float16)pf0[rr][e];
                            xbuf[e + 4][b][k] = (_Float16)pf1[rr][e];
                        }
                    }
                }
            } else {
                if (doPipe) {
                    if (tid == 0) {
                        while (__hip_atomic_load(&flags[bg], __ATOMIC_ACQUIRE,
                                                 __HIP_MEMORY_SCOPE_AGENT) < c + 1)
                            __builtin_amdgcn_s_sleep(2);
                    }
                    __syncthreads();
                }
                const int pq = tid >> 2;
                const int b = pq >> 3, trow = pq & 7;
                const int u0 = (tid & 3) * 32;
                const _Float16* src =
                    h0ws + ((size_t)(b0 + b) * T_ + (t + trow)) * H_ + u0;
                #pragma unroll
                for (int e = 0; e < 4; ++e) {
                    half8 v = *(const half8*)(src + e * 8);
                    *(half8*)&xbuf[trow][b][u0 + e * 8] = v;
                }
            }
            __syncthreads();
        }

        const int rd = (t ^ 1) & 1;
        const int wr = t & 1;

        // ---- fragment reads hoisted: xf first, then hf ----
        half8 xf[4], hf[4];
        #pragma unroll
        for (int kt = 0; kt < 4; ++kt)
            xf[kt] = *(const half8*)&xbuf[tb][cl][kt * 32 + g * 8];
        #pragma unroll
        for (int kt = 0; kt < 4; ++kt)
            hf[kt] = *(const half8*)&hbuf[rd][cl][kt * 32 + g * 8];

        f32x4 ai0 = bias[0], ai1 = bias[1], ai2 = bias[2], ai3 = bias[3];
        f32x4 ah0 = {0,0,0,0}, ah1 = {0,0,0,0}, ah2 = {0,0,0,0}, ah3 = {0,0,0,0};
        #pragma unroll
        for (int kt = 0; kt < 4; ++kt) {
            ai0 = MFMA16(wihf[0][kt], xf[kt], ai0);
            ai1 = MFMA16(wihf[1][kt], xf[kt], ai1);
            ai2 = MFMA16(wihf[2][kt], xf[kt], ai2);
            ai3 = MFMA16(wihf[3][kt], xf[kt], ai3);
            ah0 = MFMA16(whhf[0][kt], hf[kt], ah0);
            ah1 = MFMA16(whhf[1][kt], hf[kt], ah1);
            ah2 = MFMA16(whhf[2][kt], hf[kt], ah2);
            ah3 = MFMA16(whhf[3][kt], hf[kt], ah3);
        }

        if (role == 1 && t > 0) {    // head term for h1(t-1)
            f32x4 aacc = ba4;
            #pragma unroll
            for (int kt = 0; kt < 4; ++kt) aacc = MFMA16(waf[kt], hf[kt], aacc);
            #pragma unroll
            for (int r = 0; r < 4; ++r) {
                const float a = aacc[r];
                oacc[r] += a * fmaxf(a, 0.f);
            }
        }

        half4_ h4;
        #pragma unroll
        for (int r = 0; r < 4; ++r) {
            const float i_ = ai0[r] + ah0[r];
            const float f_ = ai1[r] + ah1[r];
            const float g_ = ai2[r] + ah2[r];
            const float o_ = ai3[r] + ah3[r];
            const float is = sigm_(i_);
            const float fs = sigm_(f_);
            const float gt_ = tanh_(g_);
            const float os = sigm_(o_);
            cst[r] = fs * cst[r] + is * gt_;
            h4[r] = (_Float16)(os * tanh_(cst[r]));
        }
        const int u0 = w * 16 + g * 4;
        *(half4_*)&hbuf[wr][cl][u0] = h4;
        if (role == 0) {
            if (tb == TCH - 1) {
                // last step of chunk: store NOW so the barrier drains it
                // before the flag release (consumer visibility).
                *(half4_*)&h0ws[((size_t)(b0 + cl) * T_ + t) * H_ + u0] = h4;
            } else {
                h4p = h4;   // delayed store, issued after the barrier below
            }
        }
        __syncthreads();

        if (role == 0 && tb == TCH - 1 && doPipe) {
            if (tid == 0)
                __hip_atomic_store(&flags[bg], c + 1, __ATOMIC_RELEASE,
                                   __HIP_MEMORY_SCOPE_AGENT);
        }
    }

    if (role == 1) {
        f32x4 aacc = ba4;
        #pragma unroll
        for (int kt = 0; kt < 4; ++kt) {
            const half8 hfv = *(const half8*)&hbuf[1][cl][kt * 32 + g * 8];
            aacc = MFMA16(waf[kt], hfv, aacc);
        }
        #pragma unroll
        for (int r = 0; r < 4; ++r) {
            const float a = aacc[r];
            oacc[r] += a * fmaxf(a, 0.f);
        }
        *(f32x4*)&out[(size_t)(b0 + cl) * H_ + w * 16 + g * 4] = oacc;
    }
}

extern "C" void kernel_launch(void* const* d_in, const int* in_sizes, int n_in,
                              void* d_out, int out_size, void* d_ws, size_t ws_size,
                              hipStream_t stream) {
    const float* y    = (const float*)d_in[0];
    const float* Wih0 = (const float*)d_in[1];
    const float* Whh0 = (const float*)d_in[2];
    const float* bih0 = (const float*)d_in[3];
    const float* bhh0 = (const float*)d_in[4];
    const float* Wih1 = (const float*)d_in[5];
    const float* Whh1 = (const float*)d_in[6];
    const float* bih1 = (const float*)d_in[7];
    const float* bhh1 = (const float*)d_in[8];
    const float* Wa   = (const float*)d_in[9];
    const float* ba   = (const float*)d_in[10];
    float* out = (float*)d_out;

    const size_t H0_BYTES = (size_t)B_ * T_ * H_ * sizeof(_Float16); // 64 MiB
    _Float16* h0ws = (_Float16*)d_ws;

    if (ws_size >= H0_BYTES + 512) {
        int* flags = (int*)((char*)d_ws + H0_BYTES);
        hipMemsetAsync(flags, 0, 512, stream);
        lstm_fused<<<2 * NBG, 512, 0, stream>>>(y, Wih0, Whh0, bih0, bhh0,
                                                Wih1, Whh1, bih1, bhh1, Wa, ba,
                                                h0ws, flags, out, 0, 1);
    } else {
        lstm_fused<<<NBG, 512, 0, stream>>>(y, Wih0, Whh0, bih0, bhh0,
                                            Wih1, Whh1, bih1, bhh1, Wa, ba,
                                            h0ws, nullptr, out, 0, 0);
        lstm_fused<<<NBG, 512, 0, stream>>>(y, Wih0, Whh0, bih0, bhh0,
                                            Wih1, Whh1, bih1, bhh1, Wa, ba,
                                            h0ws, nullptr, out, 1, 0);
    }
}

// Round 6
// 859.669 us; speedup vs baseline: 1.6948x; 1.3927x over previous
//
#include <hip/hip_runtime.h>

// LSTMFeatureExtractor: 2-layer LSTM (H=128) over B=512, T=512, + a*relu(a) head.
// Round 6 = round-2 EXACTLY (best: 860us) + XCD pairing swizzle:
// blocks round-robin over 8 XCDs (blockIdx%8). Map blockIdx so each batch
// group's role-0 (producer) and role-1 (consumer) blocks share blockIdx%8 ->
// same XCD -> h0ws handoff + flag polling stay in that XCD's L2.
//   slot = blockIdx>>3 (0..7); role = slot&1; bg = (slot>>1)*8 + (blockIdx&7).
// Only other delta vs round 2: xbuf is not pre-zeroed (fully overwritten).

typedef _Float16 half8  __attribute__((ext_vector_type(8)));
typedef _Float16 half4_ __attribute__((ext_vector_type(4)));
typedef float    f32x4  __attribute__((ext_vector_type(4)));

#define H_    128
#define T_    512
#define B_    512
#define BCH   16              // batch per block
#define NBG   (B_ / BCH)      // 32 batch groups
#define TCH   8               // timesteps per chunk (pipeline granularity)
#define KPAD  136             // padded LDS row: 272B

#define LOG2E 1.44269504089f

__device__ __forceinline__ float sigm_(float x) {
    return __builtin_amdgcn_rcpf(1.f + __builtin_amdgcn_exp2f(-LOG2E * x));
}
__device__ __forceinline__ float tanh_(float x) {
    return 1.f - 2.f * __builtin_amdgcn_rcpf(1.f + __builtin_amdgcn_exp2f((2.f * LOG2E) * x));
}

#define MFMA16(A, Bv, C) __builtin_amdgcn_mfma_f32_16x16x32_f16((A), (Bv), (C), 0, 0, 0)

// role 0: layer0, x from y (fp32 [b][k][t]), h -> h0ws per step, flag release/chunk.
// role 1: layer1, x from h0ws (flag acquire), fused Wa head + sum a*relu(a) -> out.
__global__ void __launch_bounds__(512)
lstm_fused(const float* __restrict__ y,
           const float* __restrict__ Wih0, const float* __restrict__ Whh0,
           const float* __restrict__ bih0, const float* __restrict__ bhh0,
           const float* __restrict__ Wih1, const float* __restrict__ Whh1,
           const float* __restrict__ bih1, const float* __restrict__ bhh1,
           const float* __restrict__ Wa,  const float* __restrict__ ba,
           _Float16* __restrict__ h0ws,
           int* __restrict__ flags,      // nullptr => no pipeline sync
           float* __restrict__ out,
           int roleBase, int doPipe)
{
    __shared__ _Float16 xbuf[TCH][16][KPAD];
    __shared__ _Float16 hbuf[2][16][KPAD];

    const int tid  = threadIdx.x;
    const int w    = tid >> 6;
    const int l    = tid & 63;
    const int g    = l >> 4;
    const int cl   = l & 15;

    // ---- XCD-pairing block mapping (bijective) ----
    int role, bg;
    if (doPipe) {
        const int slot = blockIdx.x >> 3;            // 0..7
        role = (slot & 1) + roleBase;
        bg   = ((slot >> 1) << 3) | (blockIdx.x & 7); // 0..31
    } else {
        role = roleBase;
        bg   = blockIdx.x & 31;
    }
    const int b0 = bg * BCH;

    // ---- zero hbuf (initial h state); xbuf is fully overwritten before use ----
    {
        int* q = (int*)&hbuf[0][0][0];
        for (int i = tid; i < (int)(sizeof(hbuf) / 4); i += 512) q[i] = 0;
    }

    const float* Wih  = role ? Wih1 : Wih0;
    const float* Whh  = role ? Whh1 : Whh0;
    const float* bihp = role ? bih1 : bih0;
    const float* bhhp = role ? bhh1 : bhh0;

    // ---- weight A-fragments (lane holds A[m=l&15][k=32kt+8g+e]) ----
    half8 wihf[4][4], whhf[4][4];
    #pragma unroll
    for (int gt = 0; gt < 4; ++gt) {
        const int grow = gt * 128 + w * 16 + cl;
        #pragma unroll
        for (int kt = 0; kt < 4; ++kt) {
            const float* pa = Wih + grow * H_ + kt * 32 + g * 8;
            const float* pb = Whh + grow * H_ + kt * 32 + g * 8;
            f32x4 a0 = *(const f32x4*)(pa);
            f32x4 a1 = *(const f32x4*)(pa + 4);
            f32x4 c0 = *(const f32x4*)(pb);
            f32x4 c1 = *(const f32x4*)(pb + 4);
            half8 fa, fb;
            #pragma unroll
            for (int e = 0; e < 4; ++e) {
                fa[e] = (_Float16)a0[e]; fa[e + 4] = (_Float16)a1[e];
                fb[e] = (_Float16)c0[e]; fb[e + 4] = (_Float16)c1[e];
            }
            wihf[gt][kt] = fa; whhf[gt][kt] = fb;
        }
    }

    f32x4 bias[4];
    #pragma unroll
    for (int gt = 0; gt < 4; ++gt)
        #pragma unroll
        for (int r = 0; r < 4; ++r) {
            const int R = gt * 128 + w * 16 + g * 4 + r;
            bias[gt][r] = bihp[R] + bhhp[R];
        }

    half8 waf[4];
    f32x4 ba4  = {0.f, 0.f, 0.f, 0.f};
    f32x4 oacc = {0.f, 0.f, 0.f, 0.f};
    if (role == 1) {
        #pragma unroll
        for (int kt = 0; kt < 4; ++kt) {
            const float* p = Wa + (w * 16 + cl) * H_ + kt * 32 + g * 8;
            f32x4 a0 = *(const f32x4*)(p);
            f32x4 a1 = *(const f32x4*)(p + 4);
            half8 f;
            #pragma unroll
            for (int e = 0; e < 4; ++e) { f[e] = (_Float16)a0[e]; f[e + 4] = (_Float16)a1[e]; }
            waf[kt] = f;
        }
        #pragma unroll
        for (int r = 0; r < 4; ++r) ba4[r] = ba[w * 16 + g * 4 + r];
    }

    float cst[4] = {0.f, 0.f, 0.f, 0.f};
    __syncthreads();

    for (int t = 0; t < T_; ++t) {
        const int tb = t & (TCH - 1);
        if (tb == 0) {
            const int c = t >> 3;
            if (role == 0) {
                // stage y[b][k][t..t+7] -> xbuf (f16)
                #pragma unroll
                for (int rr = 0; rr < 4; ++rr) {
                    const int q = tid + rr * 512;
                    const int b = q >> 7, k = q & 127;
                    const float* src = y + ((size_t)((b0 + b) * H_ + k)) * T_ + t;
                    f32x4 v0 = *(const f32x4*)(src);
                    f32x4 v1 = *(const f32x4*)(src + 4);
                    #pragma unroll
                    for (int e = 0; e < 4; ++e) {
                        xbuf[e][b][k]     = (_Float16)v0[e];
                        xbuf[e + 4][b][k] = (_Float16)v1[e];
                    }
                }
            } else {
                if (doPipe) {
                    if (tid == 0) {
                        while (__hip_atomic_load(&flags[bg], __ATOMIC_ACQUIRE,
                                                 __HIP_MEMORY_SCOPE_AGENT) < c + 1)
                            __builtin_amdgcn_s_sleep(2);
                    }
                    __syncthreads();
                }
                const int pq = tid >> 2;
                const int b = pq >> 3, trow = pq & 7;
                const int u0 = (tid & 3) * 32;
                const _Float16* src =
                    h0ws + ((size_t)(b0 + b) * T_ + (t + trow)) * H_ + u0;
                #pragma unroll
                for (int e = 0; e < 4; ++e) {
                    half8 v = *(const half8*)(src + e * 8);
                    *(half8*)&xbuf[trow][b][u0 + e * 8] = v;
                }
            }
            __syncthreads();
        }

        const int rd = (t ^ 1) & 1;
        const int wr = t & 1;

        // split accumulator chains: ih (seeded with bias) and hh (zero)
        f32x4 ai0 = bias[0], ai1 = bias[1], ai2 = bias[2], ai3 = bias[3];
        f32x4 ah0 = {0,0,0,0}, ah1 = {0,0,0,0}, ah2 = {0,0,0,0}, ah3 = {0,0,0,0};
        half8 hf[4];
        #pragma unroll
        for (int kt = 0; kt < 4; ++kt) {
            const int ko = kt * 32 + g * 8;
            const half8 xf = *(const half8*)&xbuf[tb][cl][ko];
            hf[kt]         = *(const half8*)&hbuf[rd][cl][ko];
            ai0 = MFMA16(wihf[0][kt], xf, ai0);
            ai1 = MFMA16(wihf[1][kt], xf, ai1);
            ai2 = MFMA16(wihf[2][kt], xf, ai2);
            ai3 = MFMA16(wihf[3][kt], xf, ai3);
            ah0 = MFMA16(whhf[0][kt], hf[kt], ah0);
            ah1 = MFMA16(whhf[1][kt], hf[kt], ah1);
            ah2 = MFMA16(whhf[2][kt], hf[kt], ah2);
            ah3 = MFMA16(whhf[3][kt], hf[kt], ah3);
        }

        if (role == 1 && t > 0) {    // head term for h1(t-1)
            f32x4 aacc = ba4;
            #pragma unroll
            for (int kt = 0; kt < 4; ++kt) aacc = MFMA16(waf[kt], hf[kt], aacc);
            #pragma unroll
            for (int r = 0; r < 4; ++r) {
                const float a = aacc[r];
                oacc[r] += a * fmaxf(a, 0.f);
            }
        }

        half4_ h4;
        #pragma unroll
        for (int r = 0; r < 4; ++r) {
            const float i_ = ai0[r] + ah0[r];
            const float f_ = ai1[r] + ah1[r];
            const float g_ = ai2[r] + ah2[r];
            const float o_ = ai3[r] + ah3[r];
            const float is = sigm_(i_);
            const float fs = sigm_(f_);
            const float gt_ = tanh_(g_);
            const float os = sigm_(o_);
            cst[r] = fs * cst[r] + is * gt_;
            h4[r] = (_Float16)(os * tanh_(cst[r]));
        }
        const int u0 = w * 16 + g * 4;
        *(half4_*)&hbuf[wr][cl][u0] = h4;
        if (role == 0) {
            *(half4_*)&h0ws[((size_t)(b0 + cl) * T_ + t) * H_ + u0] = h4;
        }
        __syncthreads();

        if (role == 0 && tb == TCH - 1 && doPipe) {
            if (tid == 0)
                __hip_atomic_store(&flags[bg], (t >> 3) + 1, __ATOMIC_RELEASE,
                                   __HIP_MEMORY_SCOPE_AGENT);
        }
    }

    if (role == 1) {
        // final head term for h1(T-1) in hbuf[1]
        f32x4 aacc = ba4;
        #pragma unroll
        for (int kt = 0; kt < 4; ++kt) {
            const half8 hfv = *(const half8*)&hbuf[1][cl][kt * 32 + g * 8];
            aacc = MFMA16(waf[kt], hfv, aacc);
        }
        #pragma unroll
        for (int r = 0; r < 4; ++r) {
            const float a = aacc[r];
            oacc[r] += a * fmaxf(a, 0.f);
        }
        *(f32x4*)&out[(size_t)(b0 + cl) * H_ + w * 16 + g * 4] = oacc;
    }
}

extern "C" void kernel_launch(void* const* d_in, const int* in_sizes, int n_in,
                              void* d_out, int out_size, void* d_ws, size_t ws_size,
                              hipStream_t stream) {
    const float* y    = (const float*)d_in[0];
    const float* Wih0 = (const float*)d_in[1];
    const float* Whh0 = (const float*)d_in[2];
    const float* bih0 = (const float*)d_in[3];
    const float* bhh0 = (const float*)d_in[4];
    const float* Wih1 = (const float*)d_in[5];
    const float* Whh1 = (const float*)d_in[6];
    const float* bih1 = (const float*)d_in[7];
    const float* bhh1 = (const float*)d_in[8];
    const float* Wa   = (const float*)d_in[9];
    const float* ba   = (const float*)d_in[10];
    float* out = (float*)d_out;

    const size_t H0_BYTES = (size_t)B_ * T_ * H_ * sizeof(_Float16); // 64 MiB
    _Float16* h0ws = (_Float16*)d_ws;

    if (ws_size >= H0_BYTES + 512) {
        int* flags = (int*)((char*)d_ws + H0_BYTES);
        hipMemsetAsync(flags, 0, 512, stream);
        lstm_fused<<<2 * NBG, 512, 0, stream>>>(y, Wih0, Whh0, bih0, bhh0,
                                                Wih1, Whh1, bih1, bhh1, Wa, ba,
                                                h0ws, flags, out, 0, 1);
    } else {
        lstm_fused<<<NBG, 512, 0, stream>>>(y, Wih0, Whh0, bih0, bhh0,
                                            Wih1, Whh1, bih1, bhh1, Wa, ba,
                                            h0ws, nullptr, out, 0, 0);
        lstm_fused<<<NBG, 512, 0, stream>>>(y, Wih0, Whh0, bih0, bhh0,
                                            Wih1, Whh1, bih1, bhh1, Wa, ba,
                                            h0ws, nullptr, out, 1, 0);
    }
}

// Round 7
// 859.638 us; speedup vs baseline: 1.6949x; 1.0000x over previous
//
#include <hip/hip_runtime.h>

// LSTMFeatureExtractor: 2-layer LSTM (H=128) over B=512, T=512, + a*relu(a) head.
// Round 7 = round-6 base (tied best, 860us) + ONE change: mid-chunk step
// barriers are lgkm-only (s_waitcnt lgkmcnt(0) + s_barrier), NOT __syncthreads.
// __syncthreads drains vmcnt(0) too, which parks the producer's per-step h0ws
// global store ack on the 512-step critical path (~400-900cyc). LDS correctness
// only needs lgkmcnt(0); h0ws visibility is only needed at chunk end, where the
// full __syncthreads + agent-release flag store is kept unchanged.

typedef _Float16 half8  __attribute__((ext_vector_type(8)));
typedef _Float16 half4_ __attribute__((ext_vector_type(4)));
typedef float    f32x4  __attribute__((ext_vector_type(4)));

#define H_    128
#define T_    512
#define B_    512
#define BCH   16              // batch per block
#define NBG   (B_ / BCH)      // 32 batch groups
#define TCH   8               // timesteps per chunk (pipeline granularity)
#define KPAD  136             // padded LDS row: 272B

#define LOG2E 1.44269504089f

__device__ __forceinline__ float sigm_(float x) {
    return __builtin_amdgcn_rcpf(1.f + __builtin_amdgcn_exp2f(-LOG2E * x));
}
__device__ __forceinline__ float tanh_(float x) {
    return 1.f - 2.f * __builtin_amdgcn_rcpf(1.f + __builtin_amdgcn_exp2f((2.f * LOG2E) * x));
}

// LDS-only barrier: orders ds ops across the block without draining vmcnt.
// sched_barrier(0) fences per guide rule #18 (compiler may otherwise hoist
// register-only ops past an inline-asm waitcnt / move mem ops across s_barrier).
__device__ __forceinline__ void lds_barrier() {
    __builtin_amdgcn_sched_barrier(0);
    asm volatile("s_waitcnt lgkmcnt(0)" ::: "memory");
    __builtin_amdgcn_sched_barrier(0);
    __builtin_amdgcn_s_barrier();
    __builtin_amdgcn_sched_barrier(0);
}

#define MFMA16(A, Bv, C) __builtin_amdgcn_mfma_f32_16x16x32_f16((A), (Bv), (C), 0, 0, 0)

// role 0: layer0, x from y (fp32 [b][k][t]), h -> h0ws per step, flag release/chunk.
// role 1: layer1, x from h0ws (flag acquire), fused Wa head + sum a*relu(a) -> out.
__global__ void __launch_bounds__(512)
lstm_fused(const float* __restrict__ y,
           const float* __restrict__ Wih0, const float* __restrict__ Whh0,
           const float* __restrict__ bih0, const float* __restrict__ bhh0,
           const float* __restrict__ Wih1, const float* __restrict__ Whh1,
           const float* __restrict__ bih1, const float* __restrict__ bhh1,
           const float* __restrict__ Wa,  const float* __restrict__ ba,
           _Float16* __restrict__ h0ws,
           int* __restrict__ flags,      // nullptr => no pipeline sync
           float* __restrict__ out,
           int roleBase, int doPipe)
{
    __shared__ _Float16 xbuf[TCH][16][KPAD];
    __shared__ _Float16 hbuf[2][16][KPAD];

    const int tid  = threadIdx.x;
    const int w    = tid >> 6;
    const int l    = tid & 63;
    const int g    = l >> 4;
    const int cl   = l & 15;

    // ---- XCD-pairing block mapping (bijective; neutral but harmless) ----
    int role, bg;
    if (doPipe) {
        const int slot = blockIdx.x >> 3;            // 0..7
        role = (slot & 1) + roleBase;
        bg   = ((slot >> 1) << 3) | (blockIdx.x & 7); // 0..31
    } else {
        role = roleBase;
        bg   = blockIdx.x & 31;
    }
    const int b0 = bg * BCH;

    // ---- zero hbuf (initial h state); xbuf is fully overwritten before use ----
    {
        int* q = (int*)&hbuf[0][0][0];
        for (int i = tid; i < (int)(sizeof(hbuf) / 4); i += 512) q[i] = 0;
    }

    const float* Wih  = role ? Wih1 : Wih0;
    const float* Whh  = role ? Whh1 : Whh0;
    const float* bihp = role ? bih1 : bih0;
    const float* bhhp = role ? bhh1 : bhh0;

    // ---- weight A-fragments (lane holds A[m=l&15][k=32kt+8g+e]) ----
    half8 wihf[4][4], whhf[4][4];
    #pragma unroll
    for (int gt = 0; gt < 4; ++gt) {
        const int grow = gt * 128 + w * 16 + cl;
        #pragma unroll
        for (int kt = 0; kt < 4; ++kt) {
            const float* pa = Wih + grow * H_ + kt * 32 + g * 8;
            const float* pb = Whh + grow * H_ + kt * 32 + g * 8;
            f32x4 a0 = *(const f32x4*)(pa);
            f32x4 a1 = *(const f32x4*)(pa + 4);
            f32x4 c0 = *(const f32x4*)(pb);
            f32x4 c1 = *(const f32x4*)(pb + 4);
            half8 fa, fb;
            #pragma unroll
            for (int e = 0; e < 4; ++e) {
                fa[e] = (_Float16)a0[e]; fa[e + 4] = (_Float16)a1[e];
                fb[e] = (_Float16)c0[e]; fb[e + 4] = (_Float16)c1[e];
            }
            wihf[gt][kt] = fa; whhf[gt][kt] = fb;
        }
    }

    f32x4 bias[4];
    #pragma unroll
    for (int gt = 0; gt < 4; ++gt)
        #pragma unroll
        for (int r = 0; r < 4; ++r) {
            const int R = gt * 128 + w * 16 + g * 4 + r;
            bias[gt][r] = bihp[R] + bhhp[R];
        }

    half8 waf[4];
    f32x4 ba4  = {0.f, 0.f, 0.f, 0.f};
    f32x4 oacc = {0.f, 0.f, 0.f, 0.f};
    if (role == 1) {
        #pragma unroll
        for (int kt = 0; kt < 4; ++kt) {
            const float* p = Wa + (w * 16 + cl) * H_ + kt * 32 + g * 8;
            f32x4 a0 = *(const f32x4*)(p);
            f32x4 a1 = *(const f32x4*)(p + 4);
            half8 f;
            #pragma unroll
            for (int e = 0; e < 4; ++e) { f[e] = (_Float16)a0[e]; f[e + 4] = (_Float16)a1[e]; }
            waf[kt] = f;
        }
        #pragma unroll
        for (int r = 0; r < 4; ++r) ba4[r] = ba[w * 16 + g * 4 + r];
    }

    float cst[4] = {0.f, 0.f, 0.f, 0.f};
    __syncthreads();

    for (int t = 0; t < T_; ++t) {
        const int tb = t & (TCH - 1);
        if (tb == 0) {
            const int c = t >> 3;
            if (role == 0) {
                // stage y[b][k][t..t+7] -> xbuf (f16)
                #pragma unroll
                for (int rr = 0; rr < 4; ++rr) {
                    const int q = tid + rr * 512;
                    const int b = q >> 7, k = q & 127;
                    const float* src = y + ((size_t)((b0 + b) * H_ + k)) * T_ + t;
                    f32x4 v0 = *(const f32x4*)(src);
                    f32x4 v1 = *(const f32x4*)(src + 4);
                    #pragma unroll
                    for (int e = 0; e < 4; ++e) {
                        xbuf[e][b][k]     = (_Float16)v0[e];
                        xbuf[e + 4][b][k] = (_Float16)v1[e];
                    }
                }
            } else {
                if (doPipe) {
                    if (tid == 0) {
                        while (__hip_atomic_load(&flags[bg], __ATOMIC_ACQUIRE,
                                                 __HIP_MEMORY_SCOPE_AGENT) < c + 1)
                            __builtin_amdgcn_s_sleep(2);
                    }
                    __syncthreads();
                }
                const int pq = tid >> 2;
                const int b = pq >> 3, trow = pq & 7;
                const int u0 = (tid & 3) * 32;
                const _Float16* src =
                    h0ws + ((size_t)(b0 + b) * T_ + (t + trow)) * H_ + u0;
                #pragma unroll
                for (int e = 0; e < 4; ++e) {
                    half8 v = *(const half8*)(src + e * 8);
                    *(half8*)&xbuf[trow][b][u0 + e * 8] = v;
                }
            }
            // staging writes are LDS; loads feed them via register deps ->
            // lgkm-only barrier is sufficient here.
            lds_barrier();
        }

        const int rd = (t ^ 1) & 1;
        const int wr = t & 1;

        // split accumulator chains: ih (seeded with bias) and hh (zero)
        f32x4 ai0 = bias[0], ai1 = bias[1], ai2 = bias[2], ai3 = bias[3];
        f32x4 ah0 = {0,0,0,0}, ah1 = {0,0,0,0}, ah2 = {0,0,0,0}, ah3 = {0,0,0,0};
        half8 hf[4];
        #pragma unroll
        for (int kt = 0; kt < 4; ++kt) {
            const int ko = kt * 32 + g * 8;
            const half8 xf = *(const half8*)&xbuf[tb][cl][ko];
            hf[kt]         = *(const half8*)&hbuf[rd][cl][ko];
            ai0 = MFMA16(wihf[0][kt], xf, ai0);
            ai1 = MFMA16(wihf[1][kt], xf, ai1);
            ai2 = MFMA16(wihf[2][kt], xf, ai2);
            ai3 = MFMA16(wihf[3][kt], xf, ai3);
            ah0 = MFMA16(whhf[0][kt], hf[kt], ah0);
            ah1 = MFMA16(whhf[1][kt], hf[kt], ah1);
            ah2 = MFMA16(whhf[2][kt], hf[kt], ah2);
            ah3 = MFMA16(whhf[3][kt], hf[kt], ah3);
        }

        if (role == 1 && t > 0) {    // head term for h1(t-1)
            f32x4 aacc = ba4;
            #pragma unroll
            for (int kt = 0; kt < 4; ++kt) aacc = MFMA16(waf[kt], hf[kt], aacc);
            #pragma unroll
            for (int r = 0; r < 4; ++r) {
                const float a = aacc[r];
                oacc[r] += a * fmaxf(a, 0.f);
            }
        }

        half4_ h4;
        #pragma unroll
        for (int r = 0; r < 4; ++r) {
            const float i_ = ai0[r] + ah0[r];
            const float f_ = ai1[r] + ah1[r];
            const float g_ = ai2[r] + ah2[r];
            const float o_ = ai3[r] + ah3[r];
            const float is = sigm_(i_);
            const float fs = sigm_(f_);
            const float gt_ = tanh_(g_);
            const float os = sigm_(o_);
            cst[r] = fs * cst[r] + is * gt_;
            h4[r] = (_Float16)(os * tanh_(cst[r]));
        }
        const int u0 = w * 16 + g * 4;
        *(half4_*)&hbuf[wr][cl][u0] = h4;
        if (role == 0) {
            *(half4_*)&h0ws[((size_t)(b0 + cl) * T_ + t) * H_ + u0] = h4;
        }

        if (tb == TCH - 1) {
            // chunk end: full sync (drains vmcnt -> h0ws stores visible-ordered
            // before the agent-scope release below).
            __syncthreads();
            if (role == 0 && doPipe) {
                if (tid == 0)
                    __hip_atomic_store(&flags[bg], (t >> 3) + 1, __ATOMIC_RELEASE,
                                       __HIP_MEMORY_SCOPE_AGENT);
            }
        } else {
            // mid-chunk: LDS-only barrier; h0ws store ack retires in background.
            lds_barrier();
        }
    }

    if (role == 1) {
        // final head term for h1(T-1) in hbuf[1]
        f32x4 aacc = ba4;
        #pragma unroll
        for (int kt = 0; kt < 4; ++kt) {
            const half8 hfv = *(const half8*)&hbuf[1][cl][kt * 32 + g * 8];
            aacc = MFMA16(waf[kt], hfv, aacc);
        }
        #pragma unroll
        for (int r = 0; r < 4; ++r) {
            const float a = aacc[r];
            oacc[r] += a * fmaxf(a, 0.f);
        }
        *(f32x4*)&out[(size_t)(b0 + cl) * H_ + w * 16 + g * 4] = oacc;
    }
}

extern "C" void kernel_launch(void* const* d_in, const int* in_sizes, int n_in,
                              void* d_out, int out_size, void* d_ws, size_t ws_size,
                              hipStream_t stream) {
    const float* y    = (const float*)d_in[0];
    const float* Wih0 = (const float*)d_in[1];
    const float* Whh0 = (const float*)d_in[2];
    const float* bih0 = (const float*)d_in[3];
    const float* bhh0 = (const float*)d_in[4];
    const float* Wih1 = (const float*)d_in[5];
    const float* Whh1 = (const float*)d_in[6];
    const float* bih1 = (const float*)d_in[7];
    const float* bhh1 = (const float*)d_in[8];
    const float* Wa   = (const float*)d_in[9];
    const float* ba   = (const float*)d_in[10];
    float* out = (float*)d_out;

    const size_t H0_BYTES = (size_t)B_ * T_ * H_ * sizeof(_Float16); // 64 MiB
    _Float16* h0ws = (_Float16*)d_ws;

    if (ws_size >= H0_BYTES + 512) {
        int* flags = (int*)((char*)d_ws + H0_BYTES);
        hipMemsetAsync(flags, 0, 512, stream);
        lstm_fused<<<2 * NBG, 512, 0, stream>>>(y, Wih0, Whh0, bih0, bhh0,
                                                Wih1, Whh1, bih1, bhh1, Wa, ba,
                                                h0ws, flags, out, 0, 1);
    } else {
        lstm_fused<<<NBG, 512, 0, stream>>>(y, Wih0, Whh0, bih0, bhh0,
                                            Wih1, Whh1, bih1, bhh1, Wa, ba,
                                            h0ws, nullptr, out, 0, 0);
        lstm_fused<<<NBG, 512, 0, stream>>>(y, Wih0, Whh0, bih0, bhh0,
                                            Wih1, Whh1, bih1, bhh1, Wa, ba,
                                            h0ws, nullptr, out, 1, 0);
    }
}

// Round 8
// 859.391 us; speedup vs baseline: 1.6954x; 1.0003x over previous
//
#include <hip/hip_runtime.h>

// LSTMFeatureExtractor: 2-layer LSTM (H=128) over B=512, T=512, + a*relu(a) head.
// Round 8 = round-7 base (tied best, 860us) + ONE change: 40KB dynamic LDS per
// block ("LDS hog") so static(43.5K)+dynamic(40K) = 83.5KB > 160KB/2 -> the
// dispatcher can only place ONE block per CU. Theory: fused rate (4450cyc/step)
// ~= producer(3395) + consumer(2420) - overlap => the producer/consumer blocks
// were sharing CUs and contending for LDS/trans/MFMA pipes. Forcing exclusive
// CUs should restore the pipeline rate to ~producer-solo (~724us).

typedef _Float16 half8  __attribute__((ext_vector_type(8)));
typedef _Float16 half4_ __attribute__((ext_vector_type(4)));
typedef float    f32x4  __attribute__((ext_vector_type(4)));

#define H_    128
#define T_    512
#define B_    512
#define BCH   16              // batch per block
#define NBG   (B_ / BCH)      // 32 batch groups
#define TCH   8               // timesteps per chunk (pipeline granularity)
#define KPAD  136             // padded LDS row: 272B

#define LDS_HOG 40960         // dynamic LDS bytes: force 1 block/CU

#define LOG2E 1.44269504089f

__device__ __forceinline__ float sigm_(float x) {
    return __builtin_amdgcn_rcpf(1.f + __builtin_amdgcn_exp2f(-LOG2E * x));
}
__device__ __forceinline__ float tanh_(float x) {
    return 1.f - 2.f * __builtin_amdgcn_rcpf(1.f + __builtin_amdgcn_exp2f((2.f * LOG2E) * x));
}

// LDS-only barrier: orders ds ops across the block without draining vmcnt.
__device__ __forceinline__ void lds_barrier() {
    __builtin_amdgcn_sched_barrier(0);
    asm volatile("s_waitcnt lgkmcnt(0)" ::: "memory");
    __builtin_amdgcn_sched_barrier(0);
    __builtin_amdgcn_s_barrier();
    __builtin_amdgcn_sched_barrier(0);
}

#define MFMA16(A, Bv, C) __builtin_amdgcn_mfma_f32_16x16x32_f16((A), (Bv), (C), 0, 0, 0)

// role 0: layer0, x from y (fp32 [b][k][t]), h -> h0ws per step, flag release/chunk.
// role 1: layer1, x from h0ws (flag acquire), fused Wa head + sum a*relu(a) -> out.
__global__ void __launch_bounds__(512)
lstm_fused(const float* __restrict__ y,
           const float* __restrict__ Wih0, const float* __restrict__ Whh0,
           const float* __restrict__ bih0, const float* __restrict__ bhh0,
           const float* __restrict__ Wih1, const float* __restrict__ Whh1,
           const float* __restrict__ bih1, const float* __restrict__ bhh1,
           const float* __restrict__ Wa,  const float* __restrict__ ba,
           _Float16* __restrict__ h0ws,
           int* __restrict__ flags,      // nullptr => no pipeline sync
           float* __restrict__ out,
           int roleBase, int doPipe)
{
    __shared__ _Float16 xbuf[TCH][16][KPAD];
    __shared__ _Float16 hbuf[2][16][KPAD];

    const int tid  = threadIdx.x;
    const int w    = tid >> 6;
    const int l    = tid & 63;
    const int g    = l >> 4;
    const int cl   = l & 15;

    // ---- XCD-pairing block mapping (bijective; neutral but harmless) ----
    int role, bg;
    if (doPipe) {
        const int slot = blockIdx.x >> 3;            // 0..7
        role = (slot & 1) + roleBase;
        bg   = ((slot >> 1) << 3) | (blockIdx.x & 7); // 0..31
    } else {
        role = roleBase;
        bg   = blockIdx.x & 31;
    }
    const int b0 = bg * BCH;

    // ---- zero hbuf (initial h state); xbuf is fully overwritten before use ----
    {
        int* q = (int*)&hbuf[0][0][0];
        for (int i = tid; i < (int)(sizeof(hbuf) / 4); i += 512) q[i] = 0;
    }

    const float* Wih  = role ? Wih1 : Wih0;
    const float* Whh  = role ? Whh1 : Whh0;
    const float* bihp = role ? bih1 : bih0;
    const float* bhhp = role ? bhh1 : bhh0;

    // ---- weight A-fragments (lane holds A[m=l&15][k=32kt+8g+e]) ----
    half8 wihf[4][4], whhf[4][4];
    #pragma unroll
    for (int gt = 0; gt < 4; ++gt) {
        const int grow = gt * 128 + w * 16 + cl;
        #pragma unroll
        for (int kt = 0; kt < 4; ++kt) {
            const float* pa = Wih + grow * H_ + kt * 32 + g * 8;
            const float* pb = Whh + grow * H_ + kt * 32 + g * 8;
            f32x4 a0 = *(const f32x4*)(pa);
            f32x4 a1 = *(const f32x4*)(pa + 4);
            f32x4 c0 = *(const f32x4*)(pb);
            f32x4 c1 = *(const f32x4*)(pb + 4);
            half8 fa, fb;
            #pragma unroll
            for (int e = 0; e < 4; ++e) {
                fa[e] = (_Float16)a0[e]; fa[e + 4] = (_Float16)a1[e];
                fb[e] = (_Float16)c0[e]; fb[e + 4] = (_Float16)c1[e];
            }
            wihf[gt][kt] = fa; whhf[gt][kt] = fb;
        }
    }

    f32x4 bias[4];
    #pragma unroll
    for (int gt = 0; gt < 4; ++gt)
        #pragma unroll
        for (int r = 0; r < 4; ++r) {
            const int R = gt * 128 + w * 16 + g * 4 + r;
            bias[gt][r] = bihp[R] + bhhp[R];
        }

    half8 waf[4];
    f32x4 ba4  = {0.f, 0.f, 0.f, 0.f};
    f32x4 oacc = {0.f, 0.f, 0.f, 0.f};
    if (role == 1) {
        #pragma unroll
        for (int kt = 0; kt < 4; ++kt) {
            const float* p = Wa + (w * 16 + cl) * H_ + kt * 32 + g * 8;
            f32x4 a0 = *(const f32x4*)(p);
            f32x4 a1 = *(const f32x4*)(p + 4);
            half8 f;
            #pragma unroll
            for (int e = 0; e < 4; ++e) { f[e] = (_Float16)a0[e]; f[e + 4] = (_Float16)a1[e]; }
            waf[kt] = f;
        }
        #pragma unroll
        for (int r = 0; r < 4; ++r) ba4[r] = ba[w * 16 + g * 4 + r];
    }

    float cst[4] = {0.f, 0.f, 0.f, 0.f};
    __syncthreads();

    for (int t = 0; t < T_; ++t) {
        const int tb = t & (TCH - 1);
        if (tb == 0) {
            const int c = t >> 3;
            if (role == 0) {
                // stage y[b][k][t..t+7] -> xbuf (f16)
                #pragma unroll
                for (int rr = 0; rr < 4; ++rr) {
                    const int q = tid + rr * 512;
                    const int b = q >> 7, k = q & 127;
                    const float* src = y + ((size_t)((b0 + b) * H_ + k)) * T_ + t;
                    f32x4 v0 = *(const f32x4*)(src);
                    f32x4 v1 = *(const f32x4*)(src + 4);
                    #pragma unroll
                    for (int e = 0; e < 4; ++e) {
                        xbuf[e][b][k]     = (_Float16)v0[e];
                        xbuf[e + 4][b][k] = (_Float16)v1[e];
                    }
                }
            } else {
                if (doPipe) {
                    if (tid == 0) {
                        while (__hip_atomic_load(&flags[bg], __ATOMIC_ACQUIRE,
                                                 __HIP_MEMORY_SCOPE_AGENT) < c + 1)
                            __builtin_amdgcn_s_sleep(2);
                    }
                    __syncthreads();
                }
                const int pq = tid >> 2;
                const int b = pq >> 3, trow = pq & 7;
                const int u0 = (tid & 3) * 32;
                const _Float16* src =
                    h0ws + ((size_t)(b0 + b) * T_ + (t + trow)) * H_ + u0;
                #pragma unroll
                for (int e = 0; e < 4; ++e) {
                    half8 v = *(const half8*)(src + e * 8);
                    *(half8*)&xbuf[trow][b][u0 + e * 8] = v;
                }
            }
            lds_barrier();
        }

        const int rd = (t ^ 1) & 1;
        const int wr = t & 1;

        // split accumulator chains: ih (seeded with bias) and hh (zero)
        f32x4 ai0 = bias[0], ai1 = bias[1], ai2 = bias[2], ai3 = bias[3];
        f32x4 ah0 = {0,0,0,0}, ah1 = {0,0,0,0}, ah2 = {0,0,0,0}, ah3 = {0,0,0,0};
        half8 hf[4];
        #pragma unroll
        for (int kt = 0; kt < 4; ++kt) {
            const int ko = kt * 32 + g * 8;
            const half8 xf = *(const half8*)&xbuf[tb][cl][ko];
            hf[kt]         = *(const half8*)&hbuf[rd][cl][ko];
            ai0 = MFMA16(wihf[0][kt], xf, ai0);
            ai1 = MFMA16(wihf[1][kt], xf, ai1);
            ai2 = MFMA16(wihf[2][kt], xf, ai2);
            ai3 = MFMA16(wihf[3][kt], xf, ai3);
            ah0 = MFMA16(whhf[0][kt], hf[kt], ah0);
            ah1 = MFMA16(whhf[1][kt], hf[kt], ah1);
            ah2 = MFMA16(whhf[2][kt], hf[kt], ah2);
            ah3 = MFMA16(whhf[3][kt], hf[kt], ah3);
        }

        if (role == 1 && t > 0) {    // head term for h1(t-1)
            f32x4 aacc = ba4;
            #pragma unroll
            for (int kt = 0; kt < 4; ++kt) aacc = MFMA16(waf[kt], hf[kt], aacc);
            #pragma unroll
            for (int r = 0; r < 4; ++r) {
                const float a = aacc[r];
                oacc[r] += a * fmaxf(a, 0.f);
            }
        }

        half4_ h4;
        #pragma unroll
        for (int r = 0; r < 4; ++r) {
            const float i_ = ai0[r] + ah0[r];
            const float f_ = ai1[r] + ah1[r];
            const float g_ = ai2[r] + ah2[r];
            const float o_ = ai3[r] + ah3[r];
            const float is = sigm_(i_);
            const float fs = sigm_(f_);
            const float gt_ = tanh_(g_);
            const float os = sigm_(o_);
            cst[r] = fs * cst[r] + is * gt_;
            h4[r] = (_Float16)(os * tanh_(cst[r]));
        }
        const int u0 = w * 16 + g * 4;
        *(half4_*)&hbuf[wr][cl][u0] = h4;
        if (role == 0) {
            *(half4_*)&h0ws[((size_t)(b0 + cl) * T_ + t) * H_ + u0] = h4;
        }

        if (tb == TCH - 1) {
            __syncthreads();
            if (role == 0 && doPipe) {
                if (tid == 0)
                    __hip_atomic_store(&flags[bg], (t >> 3) + 1, __ATOMIC_RELEASE,
                                       __HIP_MEMORY_SCOPE_AGENT);
            }
        } else {
            lds_barrier();
        }
    }

    if (role == 1) {
        // final head term for h1(T-1) in hbuf[1]
        f32x4 aacc = ba4;
        #pragma unroll
        for (int kt = 0; kt < 4; ++kt) {
            const half8 hfv = *(const half8*)&hbuf[1][cl][kt * 32 + g * 8];
            aacc = MFMA16(waf[kt], hfv, aacc);
        }
        #pragma unroll
        for (int r = 0; r < 4; ++r) {
            const float a = aacc[r];
            oacc[r] += a * fmaxf(a, 0.f);
        }
        *(f32x4*)&out[(size_t)(b0 + cl) * H_ + w * 16 + g * 4] = oacc;
    }
}

extern "C" void kernel_launch(void* const* d_in, const int* in_sizes, int n_in,
                              void* d_out, int out_size, void* d_ws, size_t ws_size,
                              hipStream_t stream) {
    const float* y    = (const float*)d_in[0];
    const float* Wih0 = (const float*)d_in[1];
    const float* Whh0 = (const float*)d_in[2];
    const float* bih0 = (const float*)d_in[3];
    const float* bhh0 = (const float*)d_in[4];
    const float* Wih1 = (const float*)d_in[5];
    const float* Whh1 = (const float*)d_in[6];
    const float* bih1 = (const float*)d_in[7];
    const float* bhh1 = (const float*)d_in[8];
    const float* Wa   = (const float*)d_in[9];
    const float* ba   = (const float*)d_in[10];
    float* out = (float*)d_out;

    const size_t H0_BYTES = (size_t)B_ * T_ * H_ * sizeof(_Float16); // 64 MiB
    _Float16* h0ws = (_Float16*)d_ws;

    if (ws_size >= H0_BYTES + 512) {
        int* flags = (int*)((char*)d_ws + H0_BYTES);
        hipMemsetAsync(flags, 0, 512, stream);
        // LDS_HOG dynamic bytes: static 43.5K + 40K = 83.5K > 160K/2
        // -> at most one block per CU (pipe-contention isolation).
        lstm_fused<<<2 * NBG, 512, LDS_HOG, stream>>>(y, Wih0, Whh0, bih0, bhh0,
                                                      Wih1, Whh1, bih1, bhh1, Wa, ba,
                                                      h0ws, flags, out, 0, 1);
    } else {
        lstm_fused<<<NBG, 512, LDS_HOG, stream>>>(y, Wih0, Whh0, bih0, bhh0,
                                                  Wih1, Whh1, bih1, bhh1, Wa, ba,
                                                  h0ws, nullptr, out, 0, 0);
        lstm_fused<<<NBG, 512, LDS_HOG, stream>>>(y, Wih0, Whh0, bih0, bhh0,
                                                  Wih1, Whh1, bih1, bhh1, Wa, ba,
                                                  h0ws, nullptr, out, 1, 0);
    }
}